// Round 5
// baseline (2353.310 us; speedup 1.0000x reference)
//
#include <hip/hip_runtime.h>
#include <math.h>

#define NLAYERS 4
#define H 4
#define C 64
#define D 64
#define HC 256     // H*C
#define D3 192     // 3*D
#define NEG 0.2f

typedef float f32x4 __attribute__((ext_vector_type(4)));
typedef short bf16x8 __attribute__((ext_vector_type(8)));
typedef unsigned short u16;

// fp32 -> bf16 round-to-nearest-even
__device__ __forceinline__ u16 f2bf(float f) {
    unsigned u = __float_as_uint(f);
    u += 0x7FFFu + ((u >> 16) & 1u);
    return (u16)(u >> 16);
}

// ---- K0: w_eff[d,h] = sum_c W_edge[d, h*C+c] * att_edge[h,c]  (one block) ----
__global__ void k_weff(const float* __restrict__ W_edge, const float* __restrict__ att_edge,
                       float* __restrict__ weff) {
    int t = threadIdx.x;
    int d = t >> 2, h = t & 3;
    float s = 0.f;
    #pragma unroll
    for (int c = 0; c < C; ++c)
        s = fmaf(W_edge[d * HC + h * C + c], att_edge[h * C + c], s);
    weff[d * H + h] = s;
}

// ---- K0b: convert W1 -> W1^T bf16, W2 -> W2^T bf16 ----
__global__ void k_cvtw(const float* __restrict__ W1, const float* __restrict__ W2,
                       u16* __restrict__ W1T, u16* __restrict__ W2T) {
    int i = blockIdx.x * 256 + threadIdx.x;
    if (i < NLAYERS * D3 * D3) {
        int l = i / (D3 * D3), r = i % (D3 * D3);
        int n = r / D3, k = r % D3;
        W1T[i] = f2bf(W1[l * D3 * D3 + k * D3 + n]);
    } else {
        int j = i - NLAYERS * D3 * D3;
        if (j < NLAYERS * D3 * D) {
            int l = j / (D3 * D), r = j % (D3 * D);
            int n = r / D3, k = r % D3;
            W2T[j] = f2bf(W2[l * D3 * D + k * D + n]);
        }
    }
}

// ---- CSR build (once per launch) ----
__global__ void k_hist(const int* __restrict__ dst, int* __restrict__ deg, int E) {
    int i = blockIdx.x * blockDim.x + threadIdx.x;
    if (i < E) atomicAdd(&deg[dst[i]], 1);
}

__global__ void k_scan(const int* __restrict__ deg, int* __restrict__ rowptr,
                       int* __restrict__ head, int N, int E) {
    __shared__ int lds[1024];
    int t = threadIdx.x;
    int chunk = (N + 1023) / 1024;
    int begin = t * chunk, end = min(begin + chunk, N);
    int sum = 0;
    for (int i = begin; i < end; ++i) sum += deg[i];
    lds[t] = sum;
    __syncthreads();
    for (int off = 1; off < 1024; off <<= 1) {
        int v = (t >= off) ? lds[t - off] : 0;
        __syncthreads();
        lds[t] += v;
        __syncthreads();
    }
    int running = (t == 0) ? 0 : lds[t - 1];
    for (int i = begin; i < end; ++i) {
        int dg = deg[i];          // read BEFORE head[i] overwrite (deg aliases head)
        rowptr[i] = running;
        head[i] = running;
        running += dg;
    }
    if (t == 0) rowptr[N] = E;
}

__global__ void k_scatter(const int* __restrict__ src, const int* __restrict__ dst,
                          int* __restrict__ head, int* __restrict__ csrpos,
                          int* __restrict__ perm_src, int E) {
    int i = blockIdx.x * blockDim.x + threadIdx.x;
    if (i < E) {
        int d = dst[i];
        int pos = atomicAdd(&head[d], 1);
        csrpos[i] = pos;
        perm_src[pos] = src[i];
    }
}

// ---- K1: x = nf @ W_lin for 4 nodes/block; a_src/a_dst via wave reductions ----
__global__ void k_nodeproj4(const float* __restrict__ nf, const float* __restrict__ W,
                            const float* __restrict__ att_s, const float* __restrict__ att_d,
                            float* __restrict__ x, float* __restrict__ a_src,
                            float* __restrict__ a_dst, int N, int relu_in) {
    int n0 = blockIdx.x * 4;
    int t = threadIdx.x;            // 0..255 -> output channel
    __shared__ float s_nf[4][D];
    {
        int i = t >> 6, d = t & 63;
        int n = n0 + i;
        float v = (n < N) ? nf[(size_t)n * D + d] : 0.f;
        if (relu_in) v = fmaxf(v, 0.f);
        s_nf[i][d] = v;
    }
    __syncthreads();
    float a0 = 0.f, a1 = 0.f, a2 = 0.f, a3 = 0.f;
    #pragma unroll
    for (int d = 0; d < D; ++d) {
        float w = W[d * HC + t];
        a0 = fmaf(s_nf[0][d], w, a0);
        a1 = fmaf(s_nf[1][d], w, a1);
        a2 = fmaf(s_nf[2][d], w, a2);
        a3 = fmaf(s_nf[3][d], w, a3);
    }
    if (n0 + 0 < N) x[(size_t)(n0 + 0) * HC + t] = a0;
    if (n0 + 1 < N) x[(size_t)(n0 + 1) * HC + t] = a1;
    if (n0 + 2 < N) x[(size_t)(n0 + 2) * HC + t] = a2;
    if (n0 + 3 < N) x[(size_t)(n0 + 3) * HC + t] = a3;
    int h = t >> 6, c = t & 63;
    float as = att_s[h * C + c], ad = att_d[h * C + c];
    float p0 = a0 * as, p1 = a1 * as, p2 = a2 * as, p3 = a3 * as;
    float q0 = a0 * ad, q1 = a1 * ad, q2 = a2 * ad, q3 = a3 * ad;
    #pragma unroll
    for (int off = 32; off; off >>= 1) {
        p0 += __shfl_xor(p0, off); p1 += __shfl_xor(p1, off);
        p2 += __shfl_xor(p2, off); p3 += __shfl_xor(p3, off);
        q0 += __shfl_xor(q0, off); q1 += __shfl_xor(q1, off);
        q2 += __shfl_xor(q2, off); q3 += __shfl_xor(q3, off);
    }
    if (c == 0) {
        if (n0 + 0 < N) { a_src[(n0 + 0) * H + h] = p0; a_dst[(n0 + 0) * H + h] = q0; }
        if (n0 + 1 < N) { a_src[(n0 + 1) * H + h] = p1; a_dst[(n0 + 1) * H + h] = q1; }
        if (n0 + 2 < N) { a_src[(n0 + 2) * H + h] = p2; a_dst[(n0 + 2) * H + h] = q2; }
        if (n0 + 3 < N) { a_src[(n0 + 3) * H + h] = p3; a_dst[(n0 + 3) * H + h] = q3; }
    }
}

// ---- K2: per-edge alpha (leaky-relu), written in CSR position. One wave per edge. ----
__global__ void k_alpha(const float* __restrict__ ef, const float* __restrict__ weff,
                        const int* __restrict__ src, const int* __restrict__ dst,
                        const float* __restrict__ a_src, const float* __restrict__ a_dst,
                        const int* __restrict__ csrpos, float* __restrict__ alpha_csr, int E) {
    int wave = (int)((blockIdx.x * blockDim.x + threadIdx.x) >> 6);
    int lane = threadIdx.x & 63;
    if (wave >= E) return;
    float efc = ef[(size_t)wave * D + lane];
    float p0 = efc * weff[lane * H + 0];
    float p1 = efc * weff[lane * H + 1];
    float p2 = efc * weff[lane * H + 2];
    float p3 = efc * weff[lane * H + 3];
    #pragma unroll
    for (int off = 32; off; off >>= 1) {
        p0 += __shfl_xor(p0, off);
        p1 += __shfl_xor(p1, off);
        p2 += __shfl_xor(p2, off);
        p3 += __shfl_xor(p3, off);
    }
    if (lane < 4) {
        float p = (lane == 0) ? p0 : (lane == 1) ? p1 : (lane == 2) ? p2 : p3;
        int s = src[wave], dd = dst[wave];
        float a = p + a_src[s * H + lane] + a_dst[dd * H + lane];
        a = (a > 0.f) ? a : NEG * a;
        alpha_csr[(size_t)csrpos[wave] * 4 + lane] = a;
    }
}

// ---- K3: fused per-dst GAT: segment max + exp-sum + weighted agg + bias + LN ----
// One wave per node. No atomics.
__global__ void k_gat(const float* __restrict__ x, const float* __restrict__ alpha_csr,
                      const int* __restrict__ rowptr, const int* __restrict__ perm_src,
                      const float* __restrict__ bias, const float* __restrict__ g,
                      const float* __restrict__ b, float* __restrict__ nf_ln,
                      float* __restrict__ out2, int N) {
    int n = (int)((blockIdx.x * blockDim.x + threadIdx.x) >> 6);
    int lane = threadIdx.x & 63;
    if (n >= N) return;
    int s = rowptr[n], e = rowptr[n + 1];
    int deg = e - s;
    // pass A: per-head max
    float m0 = -1e30f, m1 = -1e30f, m2 = -1e30f, m3 = -1e30f;
    for (int i = lane; i < deg; i += 64) {
        const float4 a = *(const float4*)&alpha_csr[(size_t)(s + i) * 4];
        m0 = fmaxf(m0, a.x); m1 = fmaxf(m1, a.y);
        m2 = fmaxf(m2, a.z); m3 = fmaxf(m3, a.w);
    }
    #pragma unroll
    for (int off = 32; off; off >>= 1) {
        m0 = fmaxf(m0, __shfl_xor(m0, off)); m1 = fmaxf(m1, __shfl_xor(m1, off));
        m2 = fmaxf(m2, __shfl_xor(m2, off)); m3 = fmaxf(m3, __shfl_xor(m3, off));
    }
    // pass B: per-head sum of exp
    float d0 = 0.f, d1 = 0.f, d2 = 0.f, d3 = 0.f;
    for (int i = lane; i < deg; i += 64) {
        const float4 a = *(const float4*)&alpha_csr[(size_t)(s + i) * 4];
        d0 += expf(a.x - m0); d1 += expf(a.y - m1);
        d2 += expf(a.z - m2); d3 += expf(a.w - m3);
    }
    #pragma unroll
    for (int off = 32; off; off >>= 1) {
        d0 += __shfl_xor(d0, off); d1 += __shfl_xor(d1, off);
        d2 += __shfl_xor(d2, off); d3 += __shfl_xor(d3, off);
    }
    float i0 = 0.25f / (d0 + 1e-16f), i1 = 0.25f / (d1 + 1e-16f);
    float i2 = 0.25f / (d2 + 1e-16f), i3 = 0.25f / (d3 + 1e-16f);
    // pass C: aggregate, lane = output channel; per-edge scalars wave-uniform
    float acc = 0.f;
    for (int j = 0; j < deg; ++j) {
        const float4 a = *(const float4*)&alpha_csr[(size_t)(s + j) * 4];
        int sidx = perm_src[s + j];
        float w0 = expf(a.x - m0) * i0;
        float w1 = expf(a.y - m1) * i1;
        float w2 = expf(a.z - m2) * i2;
        float w3 = expf(a.w - m3) * i3;
        const float* xr = x + (size_t)sidx * HC;
        acc += w0 * xr[lane] + w1 * xr[64 + lane] + w2 * xr[128 + lane] + w3 * xr[192 + lane];
    }
    // bias + LN
    float v = acc + bias[lane];
    float sm = v;
    #pragma unroll
    for (int off = 32; off; off >>= 1) sm += __shfl_xor(sm, off);
    float mu = sm * (1.f / 64.f);
    float dv = v - mu;
    float q = dv * dv;
    #pragma unroll
    for (int off = 32; off; off >>= 1) q += __shfl_xor(q, off);
    float rstd = rsqrtf(q * (1.f / 64.f) + 1e-5f);
    float r = dv * rstd * g[lane] + b[lane];
    nf_ln[(size_t)n * D + lane] = r;
    if (out2) out2[(size_t)n * D + lane] = r;
}

// ---- K6: fused edge MLP with bf16 MFMA, register-resident LN. ----
// 256 threads (4 waves), 32 edges/block. LDS: A-tile + small stats arrays.
__global__ __launch_bounds__(256, 6) void k_edgemlp_mfma(
    const float* __restrict__ nf, const float* __restrict__ ef_in,
    const int* __restrict__ src, const int* __restrict__ dst,
    const u16* __restrict__ W1T, const float* __restrict__ b1,
    const float* __restrict__ lg, const float* __restrict__ lb,
    const u16* __restrict__ W2T, const float* __restrict__ b2,
    float* __restrict__ ef_out, int E) {
    __shared__ __align__(16) u16 A1[32 * 200];      // bf16 A tile (reused as A2)
    __shared__ float ps[4][32], pq[4][32];
    __shared__ float mu_s[32], rstd_s[32];
    int tid = threadIdx.x;
    int w = tid >> 6, lane = tid & 63;
    int e0 = blockIdx.x * 32;

    // ---- stage h_in = [ni+nj | |ni-nj| | ef] as bf16 into A1[e][k] ----
    #pragma unroll
    for (int it = 0; it < 8; ++it) {
        int e = it * 4 + w;
        int ge = e0 + e;
        float a = 0.f, b = 0.f, f = 0.f;
        if (ge < E) {
            int s = src[ge], dd = dst[ge];
            a = nf[(size_t)s * D + lane];
            b = nf[(size_t)dd * D + lane];
            f = ef_in[(size_t)ge * D + lane];
        }
        A1[e * 200 + lane]       = f2bf(a + b);
        A1[e * 200 + 64 + lane]  = f2bf(fabsf(a - b));
        A1[e * 200 + 128 + lane] = f2bf(f);
    }
    __syncthreads();

    // ---- GEMM1: wave w owns cols [w*48, w*48+48): 2 m-tiles x 3 n-tiles ----
    int m16 = lane & 15, quad = lane >> 4, kq = quad * 8;
    f32x4 acc[2][3];
    #pragma unroll
    for (int nt = 0; nt < 3; ++nt) {
        float bv = b1[w * 48 + nt * 16 + m16];
        #pragma unroll
        for (int mt = 0; mt < 2; ++mt) {
            acc[mt][nt][0] = bv; acc[mt][nt][1] = bv;
            acc[mt][nt][2] = bv; acc[mt][nt][3] = bv;
        }
    }
    #pragma unroll
    for (int ks = 0; ks < 6; ++ks) {
        int ko = ks * 32 + kq;
        bf16x8 af0 = *(const bf16x8*)&A1[m16 * 200 + ko];
        bf16x8 af1 = *(const bf16x8*)&A1[(16 + m16) * 200 + ko];
        #pragma unroll
        for (int nt = 0; nt < 3; ++nt) {
            bf16x8 bfr = *(const bf16x8*)&W1T[(w * 48 + nt * 16 + m16) * D3 + ko];
            acc[0][nt] = __builtin_amdgcn_mfma_f32_16x16x32_bf16(af0, bfr, acc[0][nt], 0, 0, 0);
            acc[1][nt] = __builtin_amdgcn_mfma_f32_16x16x32_bf16(af1, bfr, acc[1][nt], 0, 0, 0);
        }
    }

    // ---- LN stats from accumulators (lane holds rows mt*16+quad*4+r, 3 cols) ----
    {
        float s8[2][4], q8[2][4];
        #pragma unroll
        for (int mt = 0; mt < 2; ++mt)
            #pragma unroll
            for (int r = 0; r < 4; ++r) {
                float v0 = acc[mt][0][r], v1 = acc[mt][1][r], v2 = acc[mt][2][r];
                s8[mt][r] = v0 + v1 + v2;
                q8[mt][r] = v0 * v0 + v1 * v1 + v2 * v2;
            }
        // reduce across the 16 m16 lanes (same rows, different cols)
        #pragma unroll
        for (int off = 1; off < 16; off <<= 1) {
            #pragma unroll
            for (int mt = 0; mt < 2; ++mt)
                #pragma unroll
                for (int r = 0; r < 4; ++r) {
                    s8[mt][r] += __shfl_xor(s8[mt][r], off);
                    q8[mt][r] += __shfl_xor(q8[mt][r], off);
                }
        }
        if (m16 == 0) {
            #pragma unroll
            for (int mt = 0; mt < 2; ++mt)
                #pragma unroll
                for (int r = 0; r < 4; ++r) {
                    int row = mt * 16 + quad * 4 + r;
                    ps[w][row] = s8[mt][r];
                    pq[w][row] = q8[mt][r];
                }
        }
    }
    __syncthreads();
    if (tid < 32) {
        float s = ps[0][tid] + ps[1][tid] + ps[2][tid] + ps[3][tid];
        float q = pq[0][tid] + pq[1][tid] + pq[2][tid] + pq[3][tid];
        float mu = s * (1.f / 192.f);
        mu_s[tid] = mu;
        rstd_s[tid] = rsqrtf(q * (1.f / 192.f) - mu * mu + 1e-5f);
    }
    __syncthreads();

    // ---- LN + relu in registers, write bf16 A2 tile (overwrites A1) ----
    #pragma unroll
    for (int nt = 0; nt < 3; ++nt) {
        int col = w * 48 + nt * 16 + m16;
        float gg = lg[col], bb = lb[col];
        #pragma unroll
        for (int mt = 0; mt < 2; ++mt) {
            #pragma unroll
            for (int r = 0; r < 4; ++r) {
                int row = mt * 16 + quad * 4 + r;
                float v = (acc[mt][nt][r] - mu_s[row]) * rstd_s[row] * gg + bb;
                A1[row * 200 + col] = f2bf(fmaxf(v, 0.f));
            }
        }
    }
    __syncthreads();

    // ---- GEMM2: wave w owns cols w*16..w*16+15, 2 m-tiles ----
    int col2 = w * 16 + m16;
    f32x4 acc2[2];
    {
        float bv = b2[col2];
        #pragma unroll
        for (int mt = 0; mt < 2; ++mt) {
            acc2[mt][0] = bv; acc2[mt][1] = bv; acc2[mt][2] = bv; acc2[mt][3] = bv;
        }
    }
    #pragma unroll
    for (int ks = 0; ks < 6; ++ks) {
        int ko = ks * 32 + kq;
        bf16x8 b2f = *(const bf16x8*)&W2T[col2 * D3 + ko];
        bf16x8 a2f0 = *(const bf16x8*)&A1[m16 * 200 + ko];
        bf16x8 a2f1 = *(const bf16x8*)&A1[(16 + m16) * 200 + ko];
        acc2[0] = __builtin_amdgcn_mfma_f32_16x16x32_bf16(a2f0, b2f, acc2[0], 0, 0, 0);
        acc2[1] = __builtin_amdgcn_mfma_f32_16x16x32_bf16(a2f1, b2f, acc2[1], 0, 0, 0);
    }
    // ---- store + residual ----
    #pragma unroll
    for (int mt = 0; mt < 2; ++mt) {
        int row0 = mt * 16 + quad * 4;
        #pragma unroll
        for (int r = 0; r < 4; ++r) {
            int ge = e0 + row0 + r;
            if (ge < E) {
                size_t o = (size_t)ge * D + col2;
                ef_out[o] = acc2[mt][r] + ef_in[o];
            }
        }
    }
}

extern "C" void kernel_launch(void* const* d_in, const int* in_sizes, int n_in,
                              void* d_out, int out_size, void* d_ws, size_t ws_size,
                              hipStream_t stream) {
    const float* nf_in0   = (const float*)d_in[0];
    const float* ef_in0   = (const float*)d_in[1];
    const int*   eidx     = (const int*)d_in[2];
    const float* W_lin    = (const float*)d_in[3];
    const float* W_edge   = (const float*)d_in[4];
    const float* att_src  = (const float*)d_in[5];
    const float* att_dst  = (const float*)d_in[6];
    const float* att_edge = (const float*)d_in[7];
    const float* biasc    = (const float*)d_in[8];
    const float* ln_g     = (const float*)d_in[9];
    const float* ln_b     = (const float*)d_in[10];
    const float* eW1      = (const float*)d_in[11];
    const float* eb1      = (const float*)d_in[12];
    const float* eln_g    = (const float*)d_in[13];
    const float* eln_b    = (const float*)d_in[14];
    const float* eW2      = (const float*)d_in[15];
    const float* eb2      = (const float*)d_in[16];

    int N = in_sizes[0] / D;
    int E = in_sizes[1] / D;
    const int* srcp = eidx;
    const int* dstp = eidx + E;

    float* ws        = (float*)d_ws;
    float* x         = ws;                               // N*256
    float* alpha_csr = x + (size_t)N * HC;               // E*4 (16B aligned)
    float* a_src     = alpha_csr + (size_t)E * H;        // N*4
    float* a_dst     = a_src + (size_t)N * H;            // N*4
    float* nf_ln     = a_dst + (size_t)N * H;            // N*64
    float* weff      = nf_ln + (size_t)N * D;            // 256
    u16*   W1T       = (u16*)(weff + 256);               // L*192*192 bf16
    u16*   W2T       = W1T + (size_t)NLAYERS * D3 * D3;  // L*64*192 bf16
    int*   rowptr    = (int*)(W2T + (size_t)NLAYERS * D3 * D); // N+1
    int*   head      = rowptr + (N + 1);                 // N
    int*   csrpos    = head + N;                         // E
    int*   perm_src  = csrpos + (size_t)E;               // E

    float* out_nf = (float*)d_out;
    float* out_ef = out_nf + (size_t)N * D;

    // ---- once per launch: weights + CSR ----
    {
        int total = NLAYERS * D3 * D3 + NLAYERS * D3 * D;
        k_cvtw<<<(total + 255) / 256, 256, 0, stream>>>(eW1, eW2, W1T, W2T);
        hipMemsetAsync(head, 0, (size_t)N * sizeof(int), stream);  // head used as deg first
        k_hist<<<(E + 255) / 256, 256, 0, stream>>>(dstp, head, E);
        k_scan<<<1, 1024, 0, stream>>>(head, rowptr, head, N, E);  // deg in, head out
        k_scatter<<<(E + 255) / 256, 256, 0, stream>>>(srcp, dstp, head, csrpos, perm_src, E);
    }

    for (int l = 0; l < NLAYERS; ++l) {
        const float* nf_cur = (l == 0) ? nf_in0 : nf_ln;
        const float* ef_cur = (l == 0) ? ef_in0 : out_ef;
        int relu_in = (l > 0) ? 1 : 0;

        k_weff<<<1, 256, 0, stream>>>(W_edge + (size_t)l * D * HC, att_edge + l * H * C, weff);
        k_nodeproj4<<<(N + 3) / 4, 256, 0, stream>>>(nf_cur, W_lin + (size_t)l * D * HC,
                                                     att_src + l * H * C, att_dst + l * H * C,
                                                     x, a_src, a_dst, N, relu_in);
        k_alpha<<<(E + 3) / 4, 256, 0, stream>>>(ef_cur, weff, srcp, dstp, a_src, a_dst,
                                                 csrpos, alpha_csr, E);
        k_gat<<<(N + 3) / 4, 256, 0, stream>>>(x, alpha_csr, rowptr, perm_src,
                                               biasc + l * D, ln_g + l * D, ln_b + l * D,
                                               nf_ln, (l == NLAYERS - 1) ? out_nf : nullptr, N);
        k_edgemlp_mfma<<<(E + 31) / 32, 256, 0, stream>>>(nf_ln, ef_cur, srcp, dstp,
                                                          W1T + (size_t)l * D3 * D3, eb1 + l * D3,
                                                          eln_g + l * D3, eln_b + l * D3,
                                                          W2T + (size_t)l * D3 * D, eb2 + l * D,
                                                          out_ef, E);
    }
}

// Round 6
// 2001.252 us; speedup vs baseline: 1.1759x; 1.1759x over previous
//
#include <hip/hip_runtime.h>
#include <math.h>

#define NLAYERS 4
#define H 4
#define C 64
#define D 64
#define HC 256     // H*C
#define D3 192     // 3*D
#define NEG 0.2f

typedef float f32x4 __attribute__((ext_vector_type(4)));
typedef short bf16x8 __attribute__((ext_vector_type(8)));
typedef unsigned short u16;

// fp32 -> bf16 round-to-nearest-even
__device__ __forceinline__ u16 f2bf(float f) {
    unsigned u = __float_as_uint(f);
    u += 0x7FFFu + ((u >> 16) & 1u);
    return (u16)(u >> 16);
}

// ---- K0: per-layer small weight folds (one block, 256 thr) ----
// weff[d][h]  = sum_c W_edge[d, h*C+c] * att_edge[h,c]
// w_asd[d][h]   (o=h)   = sum_c W_lin[d, h*C+c] * att_src[h,c]
// w_asd[d][4+h] (o=4+h) = sum_c W_lin[d, h*C+c] * att_dst[h,c]
__global__ void k_weffs(const float* __restrict__ W_edge, const float* __restrict__ att_edge,
                        const float* __restrict__ W_lin, const float* __restrict__ att_s,
                        const float* __restrict__ att_d,
                        float* __restrict__ weff, float* __restrict__ w_asd) {
    int t = threadIdx.x;
    int d = t >> 2, h = t & 3;
    float se = 0.f, ss = 0.f, sd = 0.f;
    #pragma unroll
    for (int c = 0; c < C; ++c) {
        float we = W_edge[d * HC + h * C + c];
        float wl = W_lin[d * HC + h * C + c];
        se = fmaf(we, att_edge[h * C + c], se);
        ss = fmaf(wl, att_s[h * C + c], ss);
        sd = fmaf(wl, att_d[h * C + c], sd);
    }
    weff[d * 4 + h] = se;
    w_asd[d * 8 + h] = ss;
    w_asd[d * 8 + 4 + h] = sd;
}

// ---- K0b: convert W1 -> W1^T bf16, W2 -> W2^T bf16 ----
__global__ void k_cvtw(const float* __restrict__ W1, const float* __restrict__ W2,
                       u16* __restrict__ W1T, u16* __restrict__ W2T) {
    int i = blockIdx.x * 256 + threadIdx.x;
    if (i < NLAYERS * D3 * D3) {
        int l = i / (D3 * D3), r = i % (D3 * D3);
        int n = r / D3, k = r % D3;
        W1T[i] = f2bf(W1[l * D3 * D3 + k * D3 + n]);
    } else {
        int j = i - NLAYERS * D3 * D3;
        if (j < NLAYERS * D3 * D) {
            int l = j / (D3 * D), r = j % (D3 * D);
            int n = r / D3, k = r % D3;
            W2T[j] = f2bf(W2[l * D3 * D + k * D + n]);
        }
    }
}

// ---- CSR build (once per launch) ----
__global__ void k_hist(const int* __restrict__ dst, int* __restrict__ deg, int E) {
    int i = blockIdx.x * blockDim.x + threadIdx.x;
    if (i < E) atomicAdd(&deg[dst[i]], 1);
}

__global__ void k_scan(const int* __restrict__ deg, int* __restrict__ rowptr,
                       int* __restrict__ head, int N, int E) {
    __shared__ int lds[1024];
    int t = threadIdx.x;
    int chunk = (N + 1023) / 1024;
    int begin = t * chunk, end = min(begin + chunk, N);
    int sum = 0;
    for (int i = begin; i < end; ++i) sum += deg[i];
    lds[t] = sum;
    __syncthreads();
    for (int off = 1; off < 1024; off <<= 1) {
        int v = (t >= off) ? lds[t - off] : 0;
        __syncthreads();
        lds[t] += v;
        __syncthreads();
    }
    int running = (t == 0) ? 0 : lds[t - 1];
    for (int i = begin; i < end; ++i) {
        int dg = deg[i];          // read BEFORE head[i] overwrite (deg aliases head)
        rowptr[i] = running;
        head[i] = running;
        running += dg;
    }
    if (t == 0) rowptr[N] = E;
}

__global__ void k_scatter(const int* __restrict__ src, const int* __restrict__ dst,
                          int* __restrict__ head, int* __restrict__ csrpos,
                          int* __restrict__ perm_src, int E) {
    int i = blockIdx.x * blockDim.x + threadIdx.x;
    if (i < E) {
        int d = dst[i];
        int pos = atomicAdd(&head[d], 1);
        csrpos[i] = pos;
        perm_src[pos] = src[i];
    }
}

// ---- K1: x = nf @ W_lin with W staged in LDS; a_src/a_dst via folded w_asd. ----
// 256 threads, 32 nodes/block (8 groups of 4). LDS: W 64x264 pad + nf stage.
__global__ __launch_bounds__(256, 2) void k_nodeproj_lds(
    const float* __restrict__ nf, const float* __restrict__ W,
    const float* __restrict__ w_asd, float* __restrict__ x,
    float* __restrict__ a_src, float* __restrict__ a_dst, int N, int relu_in) {
    __shared__ __align__(16) float Wl[D * 264];   // cols 0..255 = W, 256..263 = w_asd
    __shared__ __align__(16) float s_nf[4][D];
    int tid = threadIdx.x;
    int n0 = blockIdx.x * 32;

    // stage W: 4096 float4s
    for (int i = tid; i < D * 64; i += 256) {
        int d = i >> 6, c4 = (i & 63) << 2;
        *(float4*)&Wl[d * 264 + c4] = *(const float4*)&W[d * 256 + c4];
    }
    for (int i = tid; i < D * 8; i += 256)
        Wl[(i >> 3) * 264 + 256 + (i & 7)] = w_asd[i];
    __syncthreads();

    for (int g = 0; g < 8; ++g) {
        int nb = n0 + g * 4;
        {
            int i = tid >> 6, dd = tid & 63;
            int n = nb + i;
            float v = (n < N) ? nf[(size_t)n * D + dd] : 0.f;
            if (relu_in) v = fmaxf(v, 0.f);
            s_nf[i][dd] = v;
        }
        __syncthreads();
        float a0 = 0.f, a1 = 0.f, a2 = 0.f, a3 = 0.f;
        #pragma unroll
        for (int d4 = 0; d4 < 16; ++d4) {
            float4 r0 = *(const float4*)&s_nf[0][d4 * 4];
            float4 r1 = *(const float4*)&s_nf[1][d4 * 4];
            float4 r2 = *(const float4*)&s_nf[2][d4 * 4];
            float4 r3 = *(const float4*)&s_nf[3][d4 * 4];
            float w0 = Wl[(d4 * 4 + 0) * 264 + tid];
            float w1 = Wl[(d4 * 4 + 1) * 264 + tid];
            float w2 = Wl[(d4 * 4 + 2) * 264 + tid];
            float w3 = Wl[(d4 * 4 + 3) * 264 + tid];
            a0 = fmaf(r0.x, w0, fmaf(r0.y, w1, fmaf(r0.z, w2, fmaf(r0.w, w3, a0))));
            a1 = fmaf(r1.x, w0, fmaf(r1.y, w1, fmaf(r1.z, w2, fmaf(r1.w, w3, a1))));
            a2 = fmaf(r2.x, w0, fmaf(r2.y, w1, fmaf(r2.z, w2, fmaf(r2.w, w3, a2))));
            a3 = fmaf(r3.x, w0, fmaf(r3.y, w1, fmaf(r3.z, w2, fmaf(r3.w, w3, a3))));
        }
        if (nb + 0 < N) x[(size_t)(nb + 0) * HC + tid] = a0;
        if (nb + 1 < N) x[(size_t)(nb + 1) * HC + tid] = a1;
        if (nb + 2 < N) x[(size_t)(nb + 2) * HC + tid] = a2;
        if (nb + 3 < N) x[(size_t)(nb + 3) * HC + tid] = a3;
        // attention scalars: 32 threads, i = node-in-group, o = 0..7 (src/dst x head)
        if (tid < 32) {
            int i = tid >> 3, o = tid & 7;
            float s = 0.f;
            #pragma unroll
            for (int d = 0; d < D; ++d)
                s = fmaf(s_nf[i][d], Wl[d * 264 + 256 + o], s);
            int n = nb + i;
            if (n < N) {
                if (o < 4) a_src[n * 4 + o] = s;
                else       a_dst[n * 4 + (o - 4)] = s;
            }
        }
        __syncthreads();
    }
}

// ---- K2: per-edge alpha (leaky-relu), written in CSR position. One wave per edge. ----
__global__ void k_alpha(const float* __restrict__ ef, const float* __restrict__ weff,
                        const int* __restrict__ src, const int* __restrict__ dst,
                        const float* __restrict__ a_src, const float* __restrict__ a_dst,
                        const int* __restrict__ csrpos, float* __restrict__ alpha_csr, int E) {
    int wave = (int)((blockIdx.x * blockDim.x + threadIdx.x) >> 6);
    int lane = threadIdx.x & 63;
    if (wave >= E) return;
    float efc = ef[(size_t)wave * D + lane];
    float p0 = efc * weff[lane * 4 + 0];
    float p1 = efc * weff[lane * 4 + 1];
    float p2 = efc * weff[lane * 4 + 2];
    float p3 = efc * weff[lane * 4 + 3];
    #pragma unroll
    for (int off = 32; off; off >>= 1) {
        p0 += __shfl_xor(p0, off);
        p1 += __shfl_xor(p1, off);
        p2 += __shfl_xor(p2, off);
        p3 += __shfl_xor(p3, off);
    }
    if (lane < 4) {
        float p = (lane == 0) ? p0 : (lane == 1) ? p1 : (lane == 2) ? p2 : p3;
        int s = src[wave], dd = dst[wave];
        float a = p + a_src[s * 4 + lane] + a_dst[dd * 4 + lane];
        a = (a > 0.f) ? a : NEG * a;
        alpha_csr[(size_t)csrpos[wave] * 4 + lane] = a;
    }
}

// ---- K3: fused per-dst GAT: segment max + exp-sum + weighted agg + bias + LN ----
// One wave per node. No atomics.
__global__ void k_gat(const float* __restrict__ x, const float* __restrict__ alpha_csr,
                      const int* __restrict__ rowptr, const int* __restrict__ perm_src,
                      const float* __restrict__ bias, const float* __restrict__ g,
                      const float* __restrict__ b, float* __restrict__ nf_ln,
                      float* __restrict__ out2, int N) {
    int n = (int)((blockIdx.x * blockDim.x + threadIdx.x) >> 6);
    int lane = threadIdx.x & 63;
    if (n >= N) return;
    int s = rowptr[n], e = rowptr[n + 1];
    int deg = e - s;
    // pass A: per-head max
    float m0 = -1e30f, m1 = -1e30f, m2 = -1e30f, m3 = -1e30f;
    for (int i = lane; i < deg; i += 64) {
        const float4 a = *(const float4*)&alpha_csr[(size_t)(s + i) * 4];
        m0 = fmaxf(m0, a.x); m1 = fmaxf(m1, a.y);
        m2 = fmaxf(m2, a.z); m3 = fmaxf(m3, a.w);
    }
    #pragma unroll
    for (int off = 32; off; off >>= 1) {
        m0 = fmaxf(m0, __shfl_xor(m0, off)); m1 = fmaxf(m1, __shfl_xor(m1, off));
        m2 = fmaxf(m2, __shfl_xor(m2, off)); m3 = fmaxf(m3, __shfl_xor(m3, off));
    }
    // pass B: per-head sum of exp
    float d0 = 0.f, d1 = 0.f, d2 = 0.f, d3 = 0.f;
    for (int i = lane; i < deg; i += 64) {
        const float4 a = *(const float4*)&alpha_csr[(size_t)(s + i) * 4];
        d0 += expf(a.x - m0); d1 += expf(a.y - m1);
        d2 += expf(a.z - m2); d3 += expf(a.w - m3);
    }
    #pragma unroll
    for (int off = 32; off; off >>= 1) {
        d0 += __shfl_xor(d0, off); d1 += __shfl_xor(d1, off);
        d2 += __shfl_xor(d2, off); d3 += __shfl_xor(d3, off);
    }
    float i0 = 0.25f / (d0 + 1e-16f), i1 = 0.25f / (d1 + 1e-16f);
    float i2 = 0.25f / (d2 + 1e-16f), i3 = 0.25f / (d3 + 1e-16f);
    // pass C: aggregate, lane = output channel; per-edge scalars wave-uniform
    float acc = 0.f;
    for (int j = 0; j < deg; ++j) {
        const float4 a = *(const float4*)&alpha_csr[(size_t)(s + j) * 4];
        int sidx = perm_src[s + j];
        float w0 = expf(a.x - m0) * i0;
        float w1 = expf(a.y - m1) * i1;
        float w2 = expf(a.z - m2) * i2;
        float w3 = expf(a.w - m3) * i3;
        const float* xr = x + (size_t)sidx * HC;
        acc += w0 * xr[lane] + w1 * xr[64 + lane] + w2 * xr[128 + lane] + w3 * xr[192 + lane];
    }
    // bias + LN
    float v = acc + bias[lane];
    float sm = v;
    #pragma unroll
    for (int off = 32; off; off >>= 1) sm += __shfl_xor(sm, off);
    float mu = sm * (1.f / 64.f);
    float dv = v - mu;
    float q = dv * dv;
    #pragma unroll
    for (int off = 32; off; off >>= 1) q += __shfl_xor(q, off);
    float rstd = rsqrtf(q * (1.f / 64.f) + 1e-5f);
    float r = dv * rstd * g[lane] + b[lane];
    nf_ln[(size_t)n * D + lane] = r;
    if (out2) out2[(size_t)n * D + lane] = r;
}

// ---- K6: fused edge MLP with bf16 MFMA, register-resident LN. ----
// 256 threads (4 waves), 32 edges/block. LDS: A-tile + small stats arrays.
__global__ __launch_bounds__(256, 6) void k_edgemlp_mfma(
    const float* __restrict__ nf, const float* __restrict__ ef_in,
    const int* __restrict__ src, const int* __restrict__ dst,
    const u16* __restrict__ W1T, const float* __restrict__ b1,
    const float* __restrict__ lg, const float* __restrict__ lb,
    const u16* __restrict__ W2T, const float* __restrict__ b2,
    float* __restrict__ ef_out, int E) {
    __shared__ __align__(16) u16 A1[32 * 200];      // bf16 A tile (reused as A2)
    __shared__ float ps[4][32], pq[4][32];
    __shared__ float mu_s[32], rstd_s[32];
    int tid = threadIdx.x;
    int w = tid >> 6, lane = tid & 63;
    int e0 = blockIdx.x * 32;

    // ---- stage h_in = [ni+nj | |ni-nj| | ef] as bf16 into A1[e][k] ----
    #pragma unroll
    for (int it = 0; it < 8; ++it) {
        int e = it * 4 + w;
        int ge = e0 + e;
        float a = 0.f, b = 0.f, f = 0.f;
        if (ge < E) {
            int s = src[ge], dd = dst[ge];
            a = nf[(size_t)s * D + lane];
            b = nf[(size_t)dd * D + lane];
            f = ef_in[(size_t)ge * D + lane];
        }
        A1[e * 200 + lane]       = f2bf(a + b);
        A1[e * 200 + 64 + lane]  = f2bf(fabsf(a - b));
        A1[e * 200 + 128 + lane] = f2bf(f);
    }
    __syncthreads();

    // ---- GEMM1: wave w owns cols [w*48, w*48+48): 2 m-tiles x 3 n-tiles ----
    int m16 = lane & 15, quad = lane >> 4, kq = quad * 8;
    f32x4 acc[2][3];
    #pragma unroll
    for (int nt = 0; nt < 3; ++nt) {
        float bv = b1[w * 48 + nt * 16 + m16];
        #pragma unroll
        for (int mt = 0; mt < 2; ++mt) {
            acc[mt][nt][0] = bv; acc[mt][nt][1] = bv;
            acc[mt][nt][2] = bv; acc[mt][nt][3] = bv;
        }
    }
    #pragma unroll
    for (int ks = 0; ks < 6; ++ks) {
        int ko = ks * 32 + kq;
        bf16x8 af0 = *(const bf16x8*)&A1[m16 * 200 + ko];
        bf16x8 af1 = *(const bf16x8*)&A1[(16 + m16) * 200 + ko];
        #pragma unroll
        for (int nt = 0; nt < 3; ++nt) {
            bf16x8 bfr = *(const bf16x8*)&W1T[(w * 48 + nt * 16 + m16) * D3 + ko];
            acc[0][nt] = __builtin_amdgcn_mfma_f32_16x16x32_bf16(af0, bfr, acc[0][nt], 0, 0, 0);
            acc[1][nt] = __builtin_amdgcn_mfma_f32_16x16x32_bf16(af1, bfr, acc[1][nt], 0, 0, 0);
        }
    }

    // ---- LN stats from accumulators (lane holds rows mt*16+quad*4+r, 3 cols) ----
    {
        float s8[2][4], q8[2][4];
        #pragma unroll
        for (int mt = 0; mt < 2; ++mt)
            #pragma unroll
            for (int r = 0; r < 4; ++r) {
                float v0 = acc[mt][0][r], v1 = acc[mt][1][r], v2 = acc[mt][2][r];
                s8[mt][r] = v0 + v1 + v2;
                q8[mt][r] = v0 * v0 + v1 * v1 + v2 * v2;
            }
        #pragma unroll
        for (int off = 1; off < 16; off <<= 1) {
            #pragma unroll
            for (int mt = 0; mt < 2; ++mt)
                #pragma unroll
                for (int r = 0; r < 4; ++r) {
                    s8[mt][r] += __shfl_xor(s8[mt][r], off);
                    q8[mt][r] += __shfl_xor(q8[mt][r], off);
                }
        }
        if (m16 == 0) {
            #pragma unroll
            for (int mt = 0; mt < 2; ++mt)
                #pragma unroll
                for (int r = 0; r < 4; ++r) {
                    int row = mt * 16 + quad * 4 + r;
                    ps[w][row] = s8[mt][r];
                    pq[w][row] = q8[mt][r];
                }
        }
    }
    __syncthreads();
    if (tid < 32) {
        float s = ps[0][tid] + ps[1][tid] + ps[2][tid] + ps[3][tid];
        float q = pq[0][tid] + pq[1][tid] + pq[2][tid] + pq[3][tid];
        float mu = s * (1.f / 192.f);
        mu_s[tid] = mu;
        rstd_s[tid] = rsqrtf(q * (1.f / 192.f) - mu * mu + 1e-5f);
    }
    __syncthreads();

    // ---- LN + relu in registers, write bf16 A2 tile (overwrites A1) ----
    #pragma unroll
    for (int nt = 0; nt < 3; ++nt) {
        int col = w * 48 + nt * 16 + m16;
        float gg = lg[col], bb = lb[col];
        #pragma unroll
        for (int mt = 0; mt < 2; ++mt) {
            #pragma unroll
            for (int r = 0; r < 4; ++r) {
                int row = mt * 16 + quad * 4 + r;
                float v = (acc[mt][nt][r] - mu_s[row]) * rstd_s[row] * gg + bb;
                A1[row * 200 + col] = f2bf(fmaxf(v, 0.f));
            }
        }
    }
    __syncthreads();

    // ---- GEMM2: wave w owns cols w*16..w*16+15, 2 m-tiles ----
    int col2 = w * 16 + m16;
    f32x4 acc2[2];
    {
        float bv = b2[col2];
        #pragma unroll
        for (int mt = 0; mt < 2; ++mt) {
            acc2[mt][0] = bv; acc2[mt][1] = bv; acc2[mt][2] = bv; acc2[mt][3] = bv;
        }
    }
    #pragma unroll
    for (int ks = 0; ks < 6; ++ks) {
        int ko = ks * 32 + kq;
        bf16x8 b2f = *(const bf16x8*)&W2T[col2 * D3 + ko];
        bf16x8 a2f0 = *(const bf16x8*)&A1[m16 * 200 + ko];
        bf16x8 a2f1 = *(const bf16x8*)&A1[(16 + m16) * 200 + ko];
        acc2[0] = __builtin_amdgcn_mfma_f32_16x16x32_bf16(a2f0, b2f, acc2[0], 0, 0, 0);
        acc2[1] = __builtin_amdgcn_mfma_f32_16x16x32_bf16(a2f1, b2f, acc2[1], 0, 0, 0);
    }
    // ---- store + residual ----
    #pragma unroll
    for (int mt = 0; mt < 2; ++mt) {
        int row0 = mt * 16 + quad * 4;
        #pragma unroll
        for (int r = 0; r < 4; ++r) {
            int ge = e0 + row0 + r;
            if (ge < E) {
                size_t o = (size_t)ge * D + col2;
                ef_out[o] = acc2[mt][r] + ef_in[o];
            }
        }
    }
}

extern "C" void kernel_launch(void* const* d_in, const int* in_sizes, int n_in,
                              void* d_out, int out_size, void* d_ws, size_t ws_size,
                              hipStream_t stream) {
    const float* nf_in0   = (const float*)d_in[0];
    const float* ef_in0   = (const float*)d_in[1];
    const int*   eidx     = (const int*)d_in[2];
    const float* W_lin    = (const float*)d_in[3];
    const float* W_edge   = (const float*)d_in[4];
    const float* att_src  = (const float*)d_in[5];
    const float* att_dst  = (const float*)d_in[6];
    const float* att_edge = (const float*)d_in[7];
    const float* biasc    = (const float*)d_in[8];
    const float* ln_g     = (const float*)d_in[9];
    const float* ln_b     = (const float*)d_in[10];
    const float* eW1      = (const float*)d_in[11];
    const float* eb1      = (const float*)d_in[12];
    const float* eln_g    = (const float*)d_in[13];
    const float* eln_b    = (const float*)d_in[14];
    const float* eW2      = (const float*)d_in[15];
    const float* eb2      = (const float*)d_in[16];

    int N = in_sizes[0] / D;
    int E = in_sizes[1] / D;
    const int* srcp = eidx;
    const int* dstp = eidx + E;

    float* ws        = (float*)d_ws;
    float* x         = ws;                               // N*256
    float* alpha_csr = x + (size_t)N * HC;               // E*4 (16B aligned)
    float* a_src     = alpha_csr + (size_t)E * H;        // N*4
    float* a_dst     = a_src + (size_t)N * H;            // N*4
    float* nf_ln     = a_dst + (size_t)N * H;            // N*64
    float* weff      = nf_ln + (size_t)N * D;            // 256
    float* w_asd     = weff + 256;                       // 512
    u16*   W1T       = (u16*)(w_asd + 512);              // L*192*192 bf16
    u16*   W2T       = W1T + (size_t)NLAYERS * D3 * D3;  // L*64*192 bf16
    int*   rowptr    = (int*)(W2T + (size_t)NLAYERS * D3 * D); // N+1
    int*   head      = rowptr + (N + 1);                 // N
    int*   csrpos    = head + N;                         // E
    int*   perm_src  = csrpos + (size_t)E;               // E

    float* out_nf = (float*)d_out;
    float* out_ef = out_nf + (size_t)N * D;

    // ---- once per launch: weights + CSR ----
    {
        int total = NLAYERS * D3 * D3 + NLAYERS * D3 * D;
        k_cvtw<<<(total + 255) / 256, 256, 0, stream>>>(eW1, eW2, W1T, W2T);
        hipMemsetAsync(head, 0, (size_t)N * sizeof(int), stream);  // head used as deg first
        k_hist<<<(E + 255) / 256, 256, 0, stream>>>(dstp, head, E);
        k_scan<<<1, 1024, 0, stream>>>(head, rowptr, head, N, E);  // deg in, head out
        k_scatter<<<(E + 255) / 256, 256, 0, stream>>>(srcp, dstp, head, csrpos, perm_src, E);
    }

    for (int l = 0; l < NLAYERS; ++l) {
        const float* nf_cur = (l == 0) ? nf_in0 : nf_ln;
        const float* ef_cur = (l == 0) ? ef_in0 : out_ef;
        int relu_in = (l > 0) ? 1 : 0;

        k_weffs<<<1, 256, 0, stream>>>(W_edge + (size_t)l * D * HC, att_edge + l * H * C,
                                       W_lin + (size_t)l * D * HC,
                                       att_src + l * H * C, att_dst + l * H * C,
                                       weff, w_asd);
        k_nodeproj_lds<<<(N + 31) / 32, 256, 0, stream>>>(nf_cur, W_lin + (size_t)l * D * HC,
                                                          w_asd, x, a_src, a_dst, N, relu_in);
        k_alpha<<<(E + 3) / 4, 256, 0, stream>>>(ef_cur, weff, srcp, dstp, a_src, a_dst,
                                                 csrpos, alpha_csr, E);
        k_gat<<<(N + 3) / 4, 256, 0, stream>>>(x, alpha_csr, rowptr, perm_src,
                                               biasc + l * D, ln_g + l * D, ln_b + l * D,
                                               nf_ln, (l == NLAYERS - 1) ? out_nf : nullptr, N);
        k_edgemlp_mfma<<<(E + 31) / 32, 256, 0, stream>>>(nf_ln, ef_cur, srcp, dstp,
                                                          W1T + (size_t)l * D3 * D3, eb1 + l * D3,
                                                          eln_g + l * D3, eln_b + l * D3,
                                                          W2T + (size_t)l * D3 * D, eb2 + l * D,
                                                          out_ef, E);
    }
}